// Round 6
// baseline (235.344 us; speedup 1.0000x reference)
//
#include <hip/hip_runtime.h>
#include <hip/hip_bf16.h>

#define HWP 9216   // H*W
#define HH  96
#define WW  96
#define CC  256    // Cin == Cout
#define NB  2

typedef __attribute__((ext_vector_type(8))) short bf16x8;
typedef __attribute__((ext_vector_type(4))) float f32x4;

__device__ inline unsigned short f2bf(float f) {
  union { __hip_bfloat16 h; unsigned short u; } cvt;
  cvt.h = __float2bfloat16(f);
  return cvt.u;
}
__device__ inline float bf_lo(unsigned int u) { return __uint_as_float(u << 16); }
__device__ inline float bf_hi(unsigned int u) { return __uint_as_float(u & 0xffff0000u); }

// ---- prep: pw_w (256x256) f32->bf16 ; off_w (18x256) f32->bf16 zero-padded to (32x256)
__global__ __launch_bounds__(256) void k_prep(const float* __restrict__ pw,
                                              const float* __restrict__ ow,
                                              unsigned short* __restrict__ pwb,
                                              unsigned short* __restrict__ wb) {
  int i = (blockIdx.x * 256 + threadIdx.x) * 4;
  if (i < CC * CC) {
    float4 v = *(const float4*)(pw + i);
    ushort4 o = make_ushort4(f2bf(v.x), f2bf(v.y), f2bf(v.z), f2bf(v.w));
    *(ushort4*)(pwb + i) = o;
  } else {
    int j = i - CC * CC;           // 0..8191
    int row = j >> 8;
    ushort4 o = make_ushort4(0, 0, 0, 0);
    if (row < 18) {
      float4 v = *(const float4*)(ow + j);
      o = make_ushort4(f2bf(v.x), f2bf(v.y), f2bf(v.z), f2bf(v.w));
    }
    *(ushort4*)(wb + j) = o;
  }
}

// ---- fused: xp = pw_w . x  (bf16 MFMA, 32 pix x 256 ch per block)
//            + offs = off_w . xp + off_b  (MFMA epilogue on the Cs tile)
// K-loop software-pipelined: global loads of slice k+1 issue in registers
// while MFMA consumes slice k from LDS.
__global__ __launch_bounds__(256) void k_main(const float* __restrict__ x,
                                              const unsigned short* __restrict__ pwb,
                                              const unsigned short* __restrict__ wb,
                                              const float* __restrict__ off_b,
                                              unsigned short* __restrict__ xpb,
                                              float* __restrict__ offs) {
  __shared__ unsigned short As[32 * 40];    // [pix][k]
  __shared__ unsigned short Bs[256 * 40];   // [n][k]
  __shared__ unsigned short Cs[32 * 264];   // [pix][ch] bf16, pad 264

  int b    = blockIdx.z;
  int pix0 = blockIdx.x * 32;
  int t    = threadIdx.x;
  int lane = t & 63;
  int w    = t >> 6;
  int mw = (w & 1) * 16;     // wave pixel tile
  int nw = (w >> 1) * 128;   // wave channel half
  int r = lane & 15, q = lane >> 4;

  f32x4 acc[8] = {};

  const float* xg = x + (size_t)b * CC * HWP + pix0;
  int sc = t >> 3;           // channel within 32-chunk
  int sp = (t & 7) * 4;      // pixel offset
  int bn = t >> 2;           // B row (with rep*64)
  int c8 = (t & 3) * 8;      // B k-offset

  // prefetch k-slice 0 into registers
  f32x4 xv = __builtin_nontemporal_load((const f32x4*)(xg + (size_t)sc * HWP + sp));
  uint4 bv[4];
#pragma unroll
  for (int rep = 0; rep < 4; ++rep)
    bv[rep] = *(const uint4*)(pwb + (rep * 64 + bn) * 256 + c8);

  for (int k0 = 0; k0 < CC; k0 += 32) {
    // commit prefetched slice to LDS
    As[(sp + 0) * 40 + sc] = f2bf(xv.x);
    As[(sp + 1) * 40 + sc] = f2bf(xv.y);
    As[(sp + 2) * 40 + sc] = f2bf(xv.z);
    As[(sp + 3) * 40 + sc] = f2bf(xv.w);
#pragma unroll
    for (int rep = 0; rep < 4; ++rep)
      *(uint4*)&Bs[(rep * 64 + bn) * 40 + c8] = bv[rep];
    __syncthreads();
    // prefetch next slice (overlaps MFMA below)
    if (k0 + 32 < CC) {
      xv = __builtin_nontemporal_load((const f32x4*)(xg + (size_t)(k0 + 32 + sc) * HWP + sp));
#pragma unroll
      for (int rep = 0; rep < 4; ++rep)
        bv[rep] = *(const uint4*)(pwb + (rep * 64 + bn) * 256 + k0 + 32 + c8);
    }
    bf16x8 a = *(const bf16x8*)&As[(mw + r) * 40 + q * 8];
#pragma unroll
    for (int nt = 0; nt < 8; ++nt) {
      bf16x8 bb = *(const bf16x8*)&Bs[(nw + nt * 16 + r) * 40 + q * 8];
      acc[nt] = __builtin_amdgcn_mfma_f32_16x16x32_bf16(a, bb, acc[nt], 0, 0, 0);
    }
    __syncthreads();
  }

  // C/D: col = lane&15 (ch), row = q*4+rr (pix) -> Cs[pix][ch] bf16
#pragma unroll
  for (int nt = 0; nt < 8; ++nt)
#pragma unroll
    for (int rr = 0; rr < 4; ++rr)
      Cs[(mw + q * 4 + rr) * 264 + nw + nt * 16 + r] = f2bf(acc[nt][rr]);
  __syncthreads();

  // write xpb coalesced: 64 B contiguous per thread
  {
    int pix = t >> 3, c32 = (t & 7) * 32;
    unsigned short* o = xpb + ((size_t)b * HWP + pix0 + pix) * CC + c32;
#pragma unroll
    for (int j = 0; j < 4; ++j)
      *(uint4*)(o + j * 8) = *(const uint4*)&Cs[pix * 264 + c32 + j * 8];
  }

  // offset epilogue: offs[pix, o] = sum_c Cs[pix][c] * wb[o][c] + off_b[o]
  {
    int mw2 = (w & 1) * 16;    // pixel tile
    int nw2 = (w >> 1) * 16;   // o tile (0 or 16)
    f32x4 oacc = {};
#pragma unroll
    for (int ks = 0; ks < CC; ks += 32) {
      bf16x8 a = *(const bf16x8*)&Cs[(mw2 + r) * 264 + ks + q * 8];
      uint4 u = *(const uint4*)(wb + (nw2 + r) * 256 + ks + q * 8);
      bf16x8 bb;
      ((uint4*)&bb)[0] = u;
      oacc = __builtin_amdgcn_mfma_f32_16x16x32_bf16(a, bb, oacc, 0, 0, 0);
    }
    int o = nw2 + r;
    if (o < 18) {
      float ob = off_b[o];
      size_t base = ((size_t)b * HWP + pix0 + mw2 + q * 4) * 20 + o;
#pragma unroll
      for (int rr = 0; rr < 4; ++rr)
        offs[base + (size_t)rr * 20] = oacc[rr] + ob;
    }
  }
}

// ---- gather + depthwise: 16 pixels/block, XCD-swizzled; LDS-staged NCHW writes.
// dw weights staged in LDS [tap][ch] (frees ~36 VGPRs -> higher occupancy).
__global__ __launch_bounds__(256, 4) void k_gather(const unsigned short* __restrict__ xp,
                                                   const float* __restrict__ offs,
                                                   const float* __restrict__ dw,
                                                   float* __restrict__ out) {
  __shared__ float Cs[16][257];
  __shared__ float dws[9][256];
  int bid = blockIdx.x;
  int sb  = (bid & 7) * 144 + (bid >> 3);
  int pix0 = sb * 16;
  int wave = threadIdx.x >> 6;
  int lane = threadIdx.x & 63;
  int c0 = lane * 4;

  // stage depthwise weights transposed: dws[tap][ch]
  {
    int ch = threadIdx.x;
#pragma unroll
    for (int kk = 0; kk < 9; ++kk)
      dws[kk][ch] = dw[ch * 9 + kk];
  }
  __syncthreads();

  int b   = pix0 / HWP;
  int hw0 = pix0 - b * HWP;
  const unsigned short* xb = xp + (size_t)b * HWP * CC;

#pragma unroll
  for (int p4 = 0; p4 < 4; ++p4) {
    int ip  = wave * 4 + p4;
    int hw  = hw0 + ip;
    int h   = hw / WW;
    int w   = hw - h * WW;

    const float* op = offs + (size_t)(pix0 + ip) * 20;
    float4 q0 = *(const float4*)(op + 0);
    float4 q1 = *(const float4*)(op + 4);
    float4 q2 = *(const float4*)(op + 8);
    float4 q3 = *(const float4*)(op + 12);
    float2 q4 = *(const float2*)(op + 16);
    float offr[18] = {q0.x,q0.y,q0.z,q0.w, q1.x,q1.y,q1.z,q1.w,
                      q2.x,q2.y,q2.z,q2.w, q3.x,q3.y,q3.z,q3.w, q4.x,q4.y};

    float acc0 = 0.f, acc1 = 0.f, acc2 = 0.f, acc3 = 0.f;
#pragma unroll
    for (int kk = 0; kk < 9; ++kk) {
      float y = (float)(h - 1 + kk / 3) + offr[2 * kk];
      float x = (float)(w - 1 + kk % 3) + offr[2 * kk + 1];
      float y0f = floorf(y), x0f = floorf(x);
      float fy = y - y0f, fx = x - x0f;
      int y0 = (int)y0f, x0 = (int)x0f;
      int y1 = y0 + 1, x1 = x0 + 1;
      bool vy0 = (y0 >= 0) & (y0 < HH);
      bool vy1 = (y1 >= 0) & (y1 < HH);
      bool vx0 = (x0 >= 0) & (x0 < WW);
      bool vx1 = (x1 >= 0) & (x1 < WW);
      int y0c = y0 < 0 ? 0 : (y0 > HH - 1 ? HH - 1 : y0);
      int y1c = y1 < 0 ? 0 : (y1 > HH - 1 ? HH - 1 : y1);
      int x0c = x0 < 0 ? 0 : (x0 > WW - 1 ? WW - 1 : x0);
      int x1c = x1 < 0 ? 0 : (x1 > WW - 1 ? WW - 1 : x1);
      float w00 = (1.f - fy) * (1.f - fx) * ((vy0 && vx0) ? 1.f : 0.f);
      float w01 = (1.f - fy) * fx         * ((vy0 && vx1) ? 1.f : 0.f);
      float w10 = fy * (1.f - fx)         * ((vy1 && vx0) ? 1.f : 0.f);
      float w11 = fy * fx                 * ((vy1 && vx1) ? 1.f : 0.f);

      uint2 u00 = *(const uint2*)(xb + (size_t)(y0c * WW + x0c) * CC + c0);
      uint2 u01 = *(const uint2*)(xb + (size_t)(y0c * WW + x1c) * CC + c0);
      uint2 u10 = *(const uint2*)(xb + (size_t)(y1c * WW + x0c) * CC + c0);
      uint2 u11 = *(const uint2*)(xb + (size_t)(y1c * WW + x1c) * CC + c0);

      float s0 = w00 * bf_lo(u00.x) + w01 * bf_lo(u01.x) + w10 * bf_lo(u10.x) + w11 * bf_lo(u11.x);
      float s1 = w00 * bf_hi(u00.x) + w01 * bf_hi(u01.x) + w10 * bf_hi(u10.x) + w11 * bf_hi(u11.x);
      float s2 = w00 * bf_lo(u00.y) + w01 * bf_lo(u01.y) + w10 * bf_lo(u10.y) + w11 * bf_lo(u11.y);
      float s3 = w00 * bf_hi(u00.y) + w01 * bf_hi(u01.y) + w10 * bf_hi(u10.y) + w11 * bf_hi(u11.y);

      float4 dv = *(const float4*)&dws[kk][c0];
      acc0 += dv.x * s0;
      acc1 += dv.y * s1;
      acc2 += dv.z * s2;
      acc3 += dv.w * s3;
    }
    *(float4*)&Cs[ip][c0] = make_float4(acc0, acc1, acc2, acc3);
  }
  __syncthreads();
  // write-out: thread t = channel, 16 consecutive pixels = 64 B contiguous per thread.
  // NORMAL stores (not nontemporal): NT caused exactly 4x WRITE_SIZE amplification.
  int ch = threadIdx.x;
  float* ob = out + (size_t)b * CC * HWP + (size_t)ch * HWP + hw0;
#pragma unroll
  for (int p4 = 0; p4 < 4; ++p4) {
    float4 v = make_float4(Cs[p4 * 4 + 0][ch], Cs[p4 * 4 + 1][ch],
                           Cs[p4 * 4 + 2][ch], Cs[p4 * 4 + 3][ch]);
    *(float4*)(ob + p4 * 4) = v;
  }
}

extern "C" void kernel_launch(void* const* d_in, const int* in_sizes, int n_in,
                              void* d_out, int out_size, void* d_ws, size_t ws_size,
                              hipStream_t stream) {
  (void)in_sizes; (void)n_in; (void)out_size; (void)ws_size;
  const float* x     = (const float*)d_in[0];
  const float* pw_w  = (const float*)d_in[1];
  const float* off_w = (const float*)d_in[2];
  const float* off_b = (const float*)d_in[3];
  const float* dw_w  = (const float*)d_in[4];
  float* out = (float*)d_out;

  char* ws = (char*)d_ws;
  unsigned short* xpb = (unsigned short*)ws;                 // B*HW*C bf16 = 9,437,184 B
  float* offs = (float*)(ws + 9437184);                      // B*HW*20 f32 = 1,474,560 B
  unsigned short* wb  = (unsigned short*)(ws + 10911744);    // 32*256 bf16 = 16,384 B
  unsigned short* pwb = (unsigned short*)(ws + 10928128);    // 256*256 bf16 = 131,072 B

  k_prep <<<(CC * CC + 32 * CC) / 1024, 256, 0, stream>>>(pw_w, off_w, pwb, wb);
  k_main <<<dim3(HWP / 32, 1, NB), 256, 0, stream>>>(x, pwb, wb, off_b, xpb, offs);
  k_gather<<<NB * HWP / 16, 256, 0, stream>>>(xpb, offs, dw_w, out);
}

// Round 7
// 149.969 us; speedup vs baseline: 1.5693x; 1.5693x over previous
//
#include <hip/hip_runtime.h>
#include <hip/hip_bf16.h>

#define HWP 9216   // H*W
#define HH  96
#define WW  96
#define CC  256    // Cin == Cout
#define NB  2

typedef __attribute__((ext_vector_type(8))) short bf16x8;
typedef __attribute__((ext_vector_type(4))) float f32x4;

__device__ inline unsigned short f2bf(float f) {
  union { __hip_bfloat16 h; unsigned short u; } cvt;
  cvt.h = __float2bfloat16(f);
  return cvt.u;
}
__device__ inline float bf_lo(unsigned int u) { return __uint_as_float(u << 16); }
__device__ inline float bf_hi(unsigned int u) { return __uint_as_float(u & 0xffff0000u); }

// ---- prep: pw_w (256x256) f32->bf16 ; off_w (18x256) f32->bf16 zero-padded to (32x256)
__global__ __launch_bounds__(256) void k_prep(const float* __restrict__ pw,
                                              const float* __restrict__ ow,
                                              unsigned short* __restrict__ pwb,
                                              unsigned short* __restrict__ wb) {
  int i = (blockIdx.x * 256 + threadIdx.x) * 4;
  if (i < CC * CC) {
    float4 v = *(const float4*)(pw + i);
    ushort4 o = make_ushort4(f2bf(v.x), f2bf(v.y), f2bf(v.z), f2bf(v.w));
    *(ushort4*)(pwb + i) = o;
  } else {
    int j = i - CC * CC;           // 0..8191
    int row = j >> 8;
    ushort4 o = make_ushort4(0, 0, 0, 0);
    if (row < 18) {
      float4 v = *(const float4*)(ow + j);
      o = make_ushort4(f2bf(v.x), f2bf(v.y), f2bf(v.z), f2bf(v.w));
    }
    *(ushort4*)(wb + j) = o;
  }
}

// ---- fused: xp = pw_w . x  (bf16 MFMA, 32 pix x 256 ch per block)
//            + offs = off_w . xp + off_b  (MFMA epilogue on the Cs tile)
// K-loop software-pipelined: global loads of slice k+1 issue in registers
// while MFMA consumes slice k from LDS.
__global__ __launch_bounds__(256) void k_main(const float* __restrict__ x,
                                              const unsigned short* __restrict__ pwb,
                                              const unsigned short* __restrict__ wb,
                                              const float* __restrict__ off_b,
                                              unsigned short* __restrict__ xpb,
                                              float* __restrict__ offs) {
  __shared__ unsigned short As[32 * 40];    // [pix][k]
  __shared__ unsigned short Bs[256 * 40];   // [n][k]
  __shared__ unsigned short Cs[32 * 264];   // [pix][ch] bf16, pad 264

  int b    = blockIdx.z;
  int pix0 = blockIdx.x * 32;
  int t    = threadIdx.x;
  int lane = t & 63;
  int w    = t >> 6;
  int mw = (w & 1) * 16;     // wave pixel tile
  int nw = (w >> 1) * 128;   // wave channel half
  int r = lane & 15, q = lane >> 4;

  f32x4 acc[8] = {};

  const float* xg = x + (size_t)b * CC * HWP + pix0;
  int sc = t >> 3;           // channel within 32-chunk
  int sp = (t & 7) * 4;      // pixel offset
  int bn = t >> 2;           // B row (with rep*64)
  int c8 = (t & 3) * 8;      // B k-offset

  // prefetch k-slice 0 into registers
  f32x4 xv = __builtin_nontemporal_load((const f32x4*)(xg + (size_t)sc * HWP + sp));
  uint4 bv[4];
#pragma unroll
  for (int rep = 0; rep < 4; ++rep)
    bv[rep] = *(const uint4*)(pwb + (rep * 64 + bn) * 256 + c8);

  for (int k0 = 0; k0 < CC; k0 += 32) {
    // commit prefetched slice to LDS
    As[(sp + 0) * 40 + sc] = f2bf(xv.x);
    As[(sp + 1) * 40 + sc] = f2bf(xv.y);
    As[(sp + 2) * 40 + sc] = f2bf(xv.z);
    As[(sp + 3) * 40 + sc] = f2bf(xv.w);
#pragma unroll
    for (int rep = 0; rep < 4; ++rep)
      *(uint4*)&Bs[(rep * 64 + bn) * 40 + c8] = bv[rep];
    __syncthreads();
    // prefetch next slice (overlaps MFMA below)
    if (k0 + 32 < CC) {
      xv = __builtin_nontemporal_load((const f32x4*)(xg + (size_t)(k0 + 32 + sc) * HWP + sp));
#pragma unroll
      for (int rep = 0; rep < 4; ++rep)
        bv[rep] = *(const uint4*)(pwb + (rep * 64 + bn) * 256 + k0 + 32 + c8);
    }
    bf16x8 a = *(const bf16x8*)&As[(mw + r) * 40 + q * 8];
#pragma unroll
    for (int nt = 0; nt < 8; ++nt) {
      bf16x8 bb = *(const bf16x8*)&Bs[(nw + nt * 16 + r) * 40 + q * 8];
      acc[nt] = __builtin_amdgcn_mfma_f32_16x16x32_bf16(a, bb, acc[nt], 0, 0, 0);
    }
    __syncthreads();
  }

  // C/D: col = lane&15 (ch), row = q*4+rr (pix) -> Cs[pix][ch] bf16
#pragma unroll
  for (int nt = 0; nt < 8; ++nt)
#pragma unroll
    for (int rr = 0; rr < 4; ++rr)
      Cs[(mw + q * 4 + rr) * 264 + nw + nt * 16 + r] = f2bf(acc[nt][rr]);
  __syncthreads();

  // write xpb coalesced: 64 B contiguous per thread
  {
    int pix = t >> 3, c32 = (t & 7) * 32;
    unsigned short* o = xpb + ((size_t)b * HWP + pix0 + pix) * CC + c32;
#pragma unroll
    for (int j = 0; j < 4; ++j)
      *(uint4*)(o + j * 8) = *(const uint4*)&Cs[pix * 264 + c32 + j * 8];
  }

  // offset epilogue: offs[pix, o] = sum_c Cs[pix][c] * wb[o][c] + off_b[o]
  {
    int mw2 = (w & 1) * 16;    // pixel tile
    int nw2 = (w >> 1) * 16;   // o tile (0 or 16)
    f32x4 oacc = {};
#pragma unroll
    for (int ks = 0; ks < CC; ks += 32) {
      bf16x8 a = *(const bf16x8*)&Cs[(mw2 + r) * 264 + ks + q * 8];
      uint4 u = *(const uint4*)(wb + (nw2 + r) * 256 + ks + q * 8);
      bf16x8 bb;
      ((uint4*)&bb)[0] = u;
      oacc = __builtin_amdgcn_mfma_f32_16x16x32_bf16(a, bb, oacc, 0, 0, 0);
    }
    int o = nw2 + r;
    if (o < 18) {
      float ob = off_b[o];
      size_t base = ((size_t)b * HWP + pix0 + mw2 + q * 4) * 20 + o;
#pragma unroll
      for (int rr = 0; rr < 4; ++rr)
        offs[base + (size_t)rr * 20] = oacc[rr] + ob;
    }
  }
}

// ---- gather + depthwise: 16 pixels/block, XCD-swizzled; LDS-staged NCHW writes.
// R5-proven config: dw weights in REGISTERS (dwr), plain launch_bounds(256).
// DO NOT add a min-waves launch-bounds arg: (256,4) capped VGPR at 64 and
// spilled offr[18] to scratch -> FETCH 194MB / WRITE 335MB, 3x slower (R6).
__global__ __launch_bounds__(256) void k_gather(const unsigned short* __restrict__ xp,
                                                const float* __restrict__ offs,
                                                const float* __restrict__ dw,
                                                float* __restrict__ out) {
  __shared__ float Cs[16][257];
  int bid = blockIdx.x;
  int sb  = (bid & 7) * 144 + (bid >> 3);
  int pix0 = sb * 16;
  int wave = threadIdx.x >> 6;
  int lane = threadIdx.x & 63;
  int c0 = lane * 4;

  float dwr[4][9];
#pragma unroll
  for (int i = 0; i < 4; ++i)
#pragma unroll
    for (int kk = 0; kk < 9; ++kk)
      dwr[i][kk] = dw[(c0 + i) * 9 + kk];

  int b   = pix0 / HWP;
  int hw0 = pix0 - b * HWP;
  const unsigned short* xb = xp + (size_t)b * HWP * CC;

#pragma unroll
  for (int p4 = 0; p4 < 4; ++p4) {
    int ip  = wave * 4 + p4;
    int hw  = hw0 + ip;
    int h   = hw / WW;
    int w   = hw - h * WW;

    const float* op = offs + (size_t)(pix0 + ip) * 20;
    float4 q0 = *(const float4*)(op + 0);
    float4 q1 = *(const float4*)(op + 4);
    float4 q2 = *(const float4*)(op + 8);
    float4 q3 = *(const float4*)(op + 12);
    float2 q4 = *(const float2*)(op + 16);
    float offr[18] = {q0.x,q0.y,q0.z,q0.w, q1.x,q1.y,q1.z,q1.w,
                      q2.x,q2.y,q2.z,q2.w, q3.x,q3.y,q3.z,q3.w, q4.x,q4.y};

    float acc0 = 0.f, acc1 = 0.f, acc2 = 0.f, acc3 = 0.f;
#pragma unroll
    for (int kk = 0; kk < 9; ++kk) {
      float y = (float)(h - 1 + kk / 3) + offr[2 * kk];
      float x = (float)(w - 1 + kk % 3) + offr[2 * kk + 1];
      float y0f = floorf(y), x0f = floorf(x);
      float fy = y - y0f, fx = x - x0f;
      int y0 = (int)y0f, x0 = (int)x0f;
      int y1 = y0 + 1, x1 = x0 + 1;
      bool vy0 = (y0 >= 0) & (y0 < HH);
      bool vy1 = (y1 >= 0) & (y1 < HH);
      bool vx0 = (x0 >= 0) & (x0 < WW);
      bool vx1 = (x1 >= 0) & (x1 < WW);
      int y0c = y0 < 0 ? 0 : (y0 > HH - 1 ? HH - 1 : y0);
      int y1c = y1 < 0 ? 0 : (y1 > HH - 1 ? HH - 1 : y1);
      int x0c = x0 < 0 ? 0 : (x0 > WW - 1 ? WW - 1 : x0);
      int x1c = x1 < 0 ? 0 : (x1 > WW - 1 ? WW - 1 : x1);
      float w00 = (1.f - fy) * (1.f - fx) * ((vy0 && vx0) ? 1.f : 0.f);
      float w01 = (1.f - fy) * fx         * ((vy0 && vx1) ? 1.f : 0.f);
      float w10 = fy * (1.f - fx)         * ((vy1 && vx0) ? 1.f : 0.f);
      float w11 = fy * fx                 * ((vy1 && vx1) ? 1.f : 0.f);

      uint2 u00 = *(const uint2*)(xb + (size_t)(y0c * WW + x0c) * CC + c0);
      uint2 u01 = *(const uint2*)(xb + (size_t)(y0c * WW + x1c) * CC + c0);
      uint2 u10 = *(const uint2*)(xb + (size_t)(y1c * WW + x0c) * CC + c0);
      uint2 u11 = *(const uint2*)(xb + (size_t)(y1c * WW + x1c) * CC + c0);

      float s0 = w00 * bf_lo(u00.x) + w01 * bf_lo(u01.x) + w10 * bf_lo(u10.x) + w11 * bf_lo(u11.x);
      float s1 = w00 * bf_hi(u00.x) + w01 * bf_hi(u01.x) + w10 * bf_hi(u10.x) + w11 * bf_hi(u11.x);
      float s2 = w00 * bf_lo(u00.y) + w01 * bf_lo(u01.y) + w10 * bf_lo(u10.y) + w11 * bf_lo(u11.y);
      float s3 = w00 * bf_hi(u00.y) + w01 * bf_hi(u01.y) + w10 * bf_hi(u10.y) + w11 * bf_hi(u11.y);

      acc0 += dwr[0][kk] * s0;
      acc1 += dwr[1][kk] * s1;
      acc2 += dwr[2][kk] * s2;
      acc3 += dwr[3][kk] * s3;
    }
    *(float4*)&Cs[ip][c0] = make_float4(acc0, acc1, acc2, acc3);
  }
  __syncthreads();
  // write-out: thread t = channel, 16 consecutive pixels = 64 B contiguous per thread.
  // NORMAL stores (not nontemporal): NT caused exactly 4x WRITE_SIZE amplification.
  int ch = threadIdx.x;
  float* ob = out + (size_t)b * CC * HWP + (size_t)ch * HWP + hw0;
#pragma unroll
  for (int p4 = 0; p4 < 4; ++p4) {
    float4 v = make_float4(Cs[p4 * 4 + 0][ch], Cs[p4 * 4 + 1][ch],
                           Cs[p4 * 4 + 2][ch], Cs[p4 * 4 + 3][ch]);
    *(float4*)(ob + p4 * 4) = v;
  }
}

extern "C" void kernel_launch(void* const* d_in, const int* in_sizes, int n_in,
                              void* d_out, int out_size, void* d_ws, size_t ws_size,
                              hipStream_t stream) {
  (void)in_sizes; (void)n_in; (void)out_size; (void)ws_size;
  const float* x     = (const float*)d_in[0];
  const float* pw_w  = (const float*)d_in[1];
  const float* off_w = (const float*)d_in[2];
  const float* off_b = (const float*)d_in[3];
  const float* dw_w  = (const float*)d_in[4];
  float* out = (float*)d_out;

  char* ws = (char*)d_ws;
  unsigned short* xpb = (unsigned short*)ws;                 // B*HW*C bf16 = 9,437,184 B
  float* offs = (float*)(ws + 9437184);                      // B*HW*20 f32 = 1,474,560 B
  unsigned short* wb  = (unsigned short*)(ws + 10911744);    // 32*256 bf16 = 16,384 B
  unsigned short* pwb = (unsigned short*)(ws + 10928128);    // 256*256 bf16 = 131,072 B

  k_prep <<<(CC * CC + 32 * CC) / 1024, 256, 0, stream>>>(pw_w, off_w, pwb, wb);
  k_main <<<dim3(HWP / 32, 1, NB), 256, 0, stream>>>(x, pwb, wb, off_b, xpb, offs);
  k_gather<<<NB * HWP / 16, 256, 0, stream>>>(xpb, offs, dw_w, out);
}

// Round 8
// 143.100 us; speedup vs baseline: 1.6446x; 1.0480x over previous
//
#include <hip/hip_runtime.h>
#include <hip/hip_bf16.h>

#define HWP 9216   // H*W
#define HH  96
#define WW  96
#define CC  256    // Cin == Cout
#define NB  2

typedef __attribute__((ext_vector_type(8))) short bf16x8;
typedef __attribute__((ext_vector_type(4))) float f32x4;

__device__ inline unsigned short f2bf(float f) {
  union { __hip_bfloat16 h; unsigned short u; } cvt;
  cvt.h = __float2bfloat16(f);
  return cvt.u;
}
__device__ inline float bf_lo(unsigned int u) { return __uint_as_float(u << 16); }
__device__ inline float bf_hi(unsigned int u) { return __uint_as_float(u & 0xffff0000u); }
__device__ inline void bf8_unpack(uint4 u, float* f) {
  f[0] = bf_lo(u.x); f[1] = bf_hi(u.x); f[2] = bf_lo(u.y); f[3] = bf_hi(u.y);
  f[4] = bf_lo(u.z); f[5] = bf_hi(u.z); f[6] = bf_lo(u.w); f[7] = bf_hi(u.w);
}

// ---- prep: pw_w (256x256) f32->bf16 ; off_w (18x256) f32->bf16 zero-padded to
// (32x256) ; dw_w (256x9) f32 -> transposed dwt (9x256) f32
__global__ __launch_bounds__(256) void k_prep(const float* __restrict__ pw,
                                              const float* __restrict__ ow,
                                              const float* __restrict__ dw,
                                              unsigned short* __restrict__ pwb,
                                              unsigned short* __restrict__ wb,
                                              float* __restrict__ dwt) {
  int i = (blockIdx.x * 256 + threadIdx.x) * 4;
  if (i < CC * CC) {
    float4 v = *(const float4*)(pw + i);
    ushort4 o = make_ushort4(f2bf(v.x), f2bf(v.y), f2bf(v.z), f2bf(v.w));
    *(ushort4*)(pwb + i) = o;
  } else if (i < CC * CC + 32 * 256) {
    int j = i - CC * CC;           // 0..8191
    int row = j >> 8;
    ushort4 o = make_ushort4(0, 0, 0, 0);
    if (row < 18) {
      float4 v = *(const float4*)(ow + j);
      o = make_ushort4(f2bf(v.x), f2bf(v.y), f2bf(v.z), f2bf(v.w));
    }
    *(ushort4*)(wb + j) = o;
  } else {
    int j2 = i - (CC * CC + 32 * 256);   // 0..2303 (step 4)
    if (j2 < 9 * 256) {
      int kk = j2 >> 8;
      int ch = j2 & 255;
      float4 v = make_float4(dw[(ch + 0) * 9 + kk], dw[(ch + 1) * 9 + kk],
                             dw[(ch + 2) * 9 + kk], dw[(ch + 3) * 9 + kk]);
      *(float4*)(dwt + j2) = v;
    }
  }
}

// ---- fused: xp = pw_w . x  (bf16 MFMA, 32 pix x 256 ch per block)
//            + offs = off_w . xp + off_b  (MFMA epilogue on the Cs tile)
// R5-proven form. NOTE: a register-prefetch software pipeline of the K-loop
// (R6/R7) REGRESSED ~10-15 us — compiler+wave overlap already covers it.
__global__ __launch_bounds__(256) void k_main(const float* __restrict__ x,
                                              const unsigned short* __restrict__ pwb,
                                              const unsigned short* __restrict__ wb,
                                              const float* __restrict__ off_b,
                                              unsigned short* __restrict__ xpb,
                                              float* __restrict__ offs) {
  __shared__ unsigned short As[32 * 40];    // [pix][k]
  __shared__ unsigned short Bs[256 * 40];   // [n][k]
  __shared__ unsigned short Cs[32 * 264];   // [pix][ch] bf16, pad 264

  int b    = blockIdx.z;
  int pix0 = blockIdx.x * 32;
  int t    = threadIdx.x;
  int lane = t & 63;
  int w    = t >> 6;
  int mw = (w & 1) * 16;     // wave pixel tile
  int nw = (w >> 1) * 128;   // wave channel half
  int r = lane & 15, q = lane >> 4;

  f32x4 acc[8] = {};

  const float* xg = x + (size_t)b * CC * HWP + pix0;
  int sc = t >> 3;           // channel within 32-chunk
  int sp = (t & 7) * 4;      // pixel offset

  for (int k0 = 0; k0 < CC; k0 += 32) {
    // A: coalesced float4 (4 pixels, 1 channel) -> in-register cvt -> transposed LDS
    f32x4 xv = __builtin_nontemporal_load((const f32x4*)(xg + (size_t)(k0 + sc) * HWP + sp));
    As[(sp + 0) * 40 + sc] = f2bf(xv.x);
    As[(sp + 1) * 40 + sc] = f2bf(xv.y);
    As[(sp + 2) * 40 + sc] = f2bf(xv.z);
    As[(sp + 3) * 40 + sc] = f2bf(xv.w);
    // B: 256 rows x 32 k slice of pwb
    const unsigned short* bg = pwb + k0;
#pragma unroll
    for (int rep = 0; rep < 4; ++rep) {
      int n  = rep * 64 + (t >> 2);
      int c8 = (t & 3) * 8;
      *(uint4*)&Bs[n * 40 + c8] = *(const uint4*)(bg + n * 256 + c8);
    }
    __syncthreads();
    bf16x8 a = *(const bf16x8*)&As[(mw + r) * 40 + q * 8];
#pragma unroll
    for (int nt = 0; nt < 8; ++nt) {
      bf16x8 bb = *(const bf16x8*)&Bs[(nw + nt * 16 + r) * 40 + q * 8];
      acc[nt] = __builtin_amdgcn_mfma_f32_16x16x32_bf16(a, bb, acc[nt], 0, 0, 0);
    }
    __syncthreads();
  }

  // C/D: col = lane&15 (ch), row = q*4+rr (pix) -> Cs[pix][ch] bf16
#pragma unroll
  for (int nt = 0; nt < 8; ++nt)
#pragma unroll
    for (int rr = 0; rr < 4; ++rr)
      Cs[(mw + q * 4 + rr) * 264 + nw + nt * 16 + r] = f2bf(acc[nt][rr]);
  __syncthreads();

  // write xpb coalesced: 64 B contiguous per thread
  {
    int pix = t >> 3, c32 = (t & 7) * 32;
    unsigned short* o = xpb + ((size_t)b * HWP + pix0 + pix) * CC + c32;
#pragma unroll
    for (int j = 0; j < 4; ++j)
      *(uint4*)(o + j * 8) = *(const uint4*)&Cs[pix * 264 + c32 + j * 8];
  }

  // offset epilogue: offs[pix, o] = sum_c Cs[pix][c] * wb[o][c] + off_b[o]
  {
    int mw2 = (w & 1) * 16;    // pixel tile
    int nw2 = (w >> 1) * 16;   // o tile (0 or 16)
    f32x4 oacc = {};
#pragma unroll
    for (int ks = 0; ks < CC; ks += 32) {
      bf16x8 a = *(const bf16x8*)&Cs[(mw2 + r) * 264 + ks + q * 8];
      uint4 u = *(const uint4*)(wb + (nw2 + r) * 256 + ks + q * 8);
      bf16x8 bb;
      ((uint4*)&bb)[0] = u;
      oacc = __builtin_amdgcn_mfma_f32_16x16x32_bf16(a, bb, oacc, 0, 0, 0);
    }
    int o = nw2 + r;
    if (o < 18) {
      float ob = off_b[o];
      size_t base = ((size_t)b * HWP + pix0 + mw2 + q * 4) * 20 + o;
#pragma unroll
      for (int rr = 0; rr < 4; ++rr)
        offs[base + (size_t)rr * 20] = oacc[rr] + ob;
    }
  }
}

// ---- gather + depthwise: 16 pixels/block, XCD-swizzled.
// Half-wave pixel pairs: lanes 0-31 own pixel A, 32-63 pixel B; each lane
// covers 8 channels (uint4 corner loads). Per-wave weight/address math serves
// 2 pixels; gather load instructions per pixel halved vs the 4-ch scheme.
// Pitfalls kept: NO launch-bounds min-wave arg (R6: VGPR cap 64 -> spills,
// 3x slower). NO nontemporal output stores (R4: 4x WRITE_SIZE).
__global__ __launch_bounds__(256) void k_gather(const unsigned short* __restrict__ xp,
                                                const float* __restrict__ offs,
                                                const float* __restrict__ dwt,
                                                float* __restrict__ out) {
  __shared__ float Cs[16][257];
  int bid = blockIdx.x;
  int sb  = (bid & 7) * 144 + (bid >> 3);
  int pix0 = sb * 16;
  int wave = threadIdx.x >> 6;
  int lane = threadIdx.x & 63;
  int half = lane >> 5;          // 0: pixel A, 1: pixel B
  int c0   = (lane & 31) * 8;    // 8 channels per lane

  int b   = pix0 / HWP;
  int hw0 = pix0 - b * HWP;
  const unsigned short* xb = xp + (size_t)b * HWP * CC;

#pragma unroll
  for (int it = 0; it < 2; ++it) {
    int ip = wave * 4 + it * 2 + half;
    int hw = hw0 + ip;
    int h  = hw / WW;
    int w  = hw - h * WW;

    const float* op = offs + (size_t)(pix0 + ip) * 20;
    float4 q0 = *(const float4*)(op + 0);
    float4 q1 = *(const float4*)(op + 4);
    float4 q2 = *(const float4*)(op + 8);
    float4 q3 = *(const float4*)(op + 12);
    float2 q4 = *(const float2*)(op + 16);
    float offr[18] = {q0.x,q0.y,q0.z,q0.w, q1.x,q1.y,q1.z,q1.w,
                      q2.x,q2.y,q2.z,q2.w, q3.x,q3.y,q3.z,q3.w, q4.x,q4.y};

    float acc[8] = {};
#pragma unroll
    for (int kk = 0; kk < 9; ++kk) {
      float y = (float)(h - 1 + kk / 3) + offr[2 * kk];
      float x = (float)(w - 1 + kk % 3) + offr[2 * kk + 1];
      float y0f = floorf(y), x0f = floorf(x);
      float fy = y - y0f, fx = x - x0f;
      int y0 = (int)y0f, x0 = (int)x0f;
      int y1 = y0 + 1, x1 = x0 + 1;
      bool vy0 = (y0 >= 0) & (y0 < HH);
      bool vy1 = (y1 >= 0) & (y1 < HH);
      bool vx0 = (x0 >= 0) & (x0 < WW);
      bool vx1 = (x1 >= 0) & (x1 < WW);
      int y0c = y0 < 0 ? 0 : (y0 > HH - 1 ? HH - 1 : y0);
      int y1c = y1 < 0 ? 0 : (y1 > HH - 1 ? HH - 1 : y1);
      int x0c = x0 < 0 ? 0 : (x0 > WW - 1 ? WW - 1 : x0);
      int x1c = x1 < 0 ? 0 : (x1 > WW - 1 ? WW - 1 : x1);
      float w00 = (1.f - fy) * (1.f - fx) * ((vy0 && vx0) ? 1.f : 0.f);
      float w01 = (1.f - fy) * fx         * ((vy0 && vx1) ? 1.f : 0.f);
      float w10 = fy * (1.f - fx)         * ((vy1 && vx0) ? 1.f : 0.f);
      float w11 = fy * fx                 * ((vy1 && vx1) ? 1.f : 0.f);

      uint4 u00 = *(const uint4*)(xb + (size_t)(y0c * WW + x0c) * CC + c0);
      uint4 u01 = *(const uint4*)(xb + (size_t)(y0c * WW + x1c) * CC + c0);
      uint4 u10 = *(const uint4*)(xb + (size_t)(y1c * WW + x0c) * CC + c0);
      uint4 u11 = *(const uint4*)(xb + (size_t)(y1c * WW + x1c) * CC + c0);
      float4 dva = *(const float4*)(dwt + kk * 256 + c0);
      float4 dvb = *(const float4*)(dwt + kk * 256 + c0 + 4);

      float f00[8], f01[8], f10[8], f11[8];
      bf8_unpack(u00, f00); bf8_unpack(u01, f01);
      bf8_unpack(u10, f10); bf8_unpack(u11, f11);
      float dvf[8] = {dva.x, dva.y, dva.z, dva.w, dvb.x, dvb.y, dvb.z, dvb.w};
#pragma unroll
      for (int m = 0; m < 8; ++m) {
        float s = w00 * f00[m] + w01 * f01[m] + w10 * f10[m] + w11 * f11[m];
        acc[m] += dvf[m] * s;
      }
    }
    *(float4*)&Cs[ip][c0]     = make_float4(acc[0], acc[1], acc[2], acc[3]);
    *(float4*)&Cs[ip][c0 + 4] = make_float4(acc[4], acc[5], acc[6], acc[7]);
  }
  __syncthreads();
  // write-out: thread t = channel, 16 consecutive pixels = 64 B contiguous.
  int ch = threadIdx.x;
  float* ob = out + (size_t)b * CC * HWP + (size_t)ch * HWP + hw0;
#pragma unroll
  for (int p4 = 0; p4 < 4; ++p4) {
    float4 v = make_float4(Cs[p4 * 4 + 0][ch], Cs[p4 * 4 + 1][ch],
                           Cs[p4 * 4 + 2][ch], Cs[p4 * 4 + 3][ch]);
    *(float4*)(ob + p4 * 4) = v;
  }
}

extern "C" void kernel_launch(void* const* d_in, const int* in_sizes, int n_in,
                              void* d_out, int out_size, void* d_ws, size_t ws_size,
                              hipStream_t stream) {
  (void)in_sizes; (void)n_in; (void)out_size; (void)ws_size;
  const float* x     = (const float*)d_in[0];
  const float* pw_w  = (const float*)d_in[1];
  const float* off_w = (const float*)d_in[2];
  const float* off_b = (const float*)d_in[3];
  const float* dw_w  = (const float*)d_in[4];
  float* out = (float*)d_out;

  char* ws = (char*)d_ws;
  unsigned short* xpb = (unsigned short*)ws;                 // B*HW*C bf16 = 9,437,184 B
  float* offs = (float*)(ws + 9437184);                      // B*HW*20 f32 = 1,474,560 B
  unsigned short* wb  = (unsigned short*)(ws + 10911744);    // 32*256 bf16 = 16,384 B
  unsigned short* pwb = (unsigned short*)(ws + 10928128);    // 256*256 bf16 = 131,072 B
  float* dwt          = (float*)(ws + 11059200);             // 9*256 f32 = 9,216 B

  k_prep <<<75, 256, 0, stream>>>(pw_w, off_w, dw_w, pwb, wb, dwt);
  k_main <<<dim3(HWP / 32, 1, NB), 256, 0, stream>>>(x, pwb, wb, off_b, xpb, offs);
  k_gather<<<NB * HWP / 16, 256, 0, stream>>>(xpb, offs, dwt, out);
}

// Round 9
// 134.730 us; speedup vs baseline: 1.7468x; 1.0621x over previous
//
#include <hip/hip_runtime.h>
#include <hip/hip_bf16.h>

#define HWP 9216   // H*W
#define HH  96
#define WW  96
#define CC  256    // Cin == Cout
#define NB  2

typedef __attribute__((ext_vector_type(8))) short bf16x8;
typedef __attribute__((ext_vector_type(4))) float f32x4;

__device__ inline unsigned short f2bf(float f) {
  union { __hip_bfloat16 h; unsigned short u; } cvt;
  cvt.h = __float2bfloat16(f);
  return cvt.u;
}
__device__ inline float bf_lo(unsigned int u) { return __uint_as_float(u << 16); }
__device__ inline float bf_hi(unsigned int u) { return __uint_as_float(u & 0xffff0000u); }

// ---- prep: pw_w (256x256) f32->bf16 ; off_w (18x256) f32->bf16 zero-padded to (32x256)
__global__ __launch_bounds__(256) void k_prep(const float* __restrict__ pw,
                                              const float* __restrict__ ow,
                                              unsigned short* __restrict__ pwb,
                                              unsigned short* __restrict__ wb) {
  int i = (blockIdx.x * 256 + threadIdx.x) * 4;
  if (i < CC * CC) {
    float4 v = *(const float4*)(pw + i);
    ushort4 o = make_ushort4(f2bf(v.x), f2bf(v.y), f2bf(v.z), f2bf(v.w));
    *(ushort4*)(pwb + i) = o;
  } else {
    int j = i - CC * CC;           // 0..8191
    int row = j >> 8;
    ushort4 o = make_ushort4(0, 0, 0, 0);
    if (row < 18) {
      float4 v = *(const float4*)(ow + j);
      o = make_ushort4(f2bf(v.x), f2bf(v.y), f2bf(v.z), f2bf(v.w));
    }
    *(ushort4*)(wb + j) = o;
  }
}

// ---- fused: xp = pw_w . x  (bf16 MFMA, 32 pix x 256 ch per block, BK=64)
//            + offs = off_w . xp + off_b  (MFMA epilogue on the Cs tile)
// BK=64 halves barrier count vs R5 (8 barriers/block instead of 16), doubling
// MFMA work per barrier. NOTE: register-prefetch pipelining (R6/R7) REGRESSED —
// do not reintroduce.
__global__ __launch_bounds__(256) void k_main(const float* __restrict__ x,
                                              const unsigned short* __restrict__ pwb,
                                              const unsigned short* __restrict__ wb,
                                              const float* __restrict__ off_b,
                                              unsigned short* __restrict__ xpb,
                                              float* __restrict__ offs) {
  __shared__ unsigned short As[32 * 72];    // [pix][k], BK=64, pad 72
  __shared__ unsigned short Bs[256 * 72];   // [n][k]
  __shared__ unsigned short Cs[32 * 264];   // [pix][ch] bf16, pad 264

  int b    = blockIdx.z;
  int pix0 = blockIdx.x * 32;
  int t    = threadIdx.x;
  int lane = t & 63;
  int w    = t >> 6;
  int mw = (w & 1) * 16;     // wave pixel tile
  int nw = (w >> 1) * 128;   // wave channel half
  int r = lane & 15, q = lane >> 4;

  f32x4 acc[8] = {};

  const float* xg = x + (size_t)b * CC * HWP + pix0;
  int sc = t >> 3;           // channel within 32-chunk
  int sp = (t & 7) * 4;      // pixel offset
  int bn = t >> 2;           // B row base
  int c8 = (t & 3) * 8;      // B k-offset

  for (int k0 = 0; k0 < CC; k0 += 64) {
    // A: two 32-ch slices, coalesced float4 -> in-register cvt -> transposed LDS
    f32x4 xv0 = __builtin_nontemporal_load((const f32x4*)(xg + (size_t)(k0 + sc) * HWP + sp));
    f32x4 xv1 = __builtin_nontemporal_load((const f32x4*)(xg + (size_t)(k0 + 32 + sc) * HWP + sp));
    As[(sp + 0) * 72 + sc] = f2bf(xv0.x);
    As[(sp + 1) * 72 + sc] = f2bf(xv0.y);
    As[(sp + 2) * 72 + sc] = f2bf(xv0.z);
    As[(sp + 3) * 72 + sc] = f2bf(xv0.w);
    As[(sp + 0) * 72 + 32 + sc] = f2bf(xv1.x);
    As[(sp + 1) * 72 + 32 + sc] = f2bf(xv1.y);
    As[(sp + 2) * 72 + 32 + sc] = f2bf(xv1.z);
    As[(sp + 3) * 72 + 32 + sc] = f2bf(xv1.w);
    // B: 256 rows x 64 k slice of pwb
#pragma unroll
    for (int rep = 0; rep < 4; ++rep) {
      int n = rep * 64 + bn;
      *(uint4*)&Bs[n * 72 + c8]      = *(const uint4*)(pwb + n * 256 + k0 + c8);
      *(uint4*)&Bs[n * 72 + 32 + c8] = *(const uint4*)(pwb + n * 256 + k0 + 32 + c8);
    }
    __syncthreads();
#pragma unroll
    for (int kh = 0; kh < 2; ++kh) {
      bf16x8 a = *(const bf16x8*)&As[(mw + r) * 72 + kh * 32 + q * 8];
#pragma unroll
      for (int nt = 0; nt < 8; ++nt) {
        bf16x8 bb = *(const bf16x8*)&Bs[(nw + nt * 16 + r) * 72 + kh * 32 + q * 8];
        acc[nt] = __builtin_amdgcn_mfma_f32_16x16x32_bf16(a, bb, acc[nt], 0, 0, 0);
      }
    }
    __syncthreads();
  }

  // C/D: col = lane&15 (ch), row = q*4+rr (pix) -> Cs[pix][ch] bf16
#pragma unroll
  for (int nt = 0; nt < 8; ++nt)
#pragma unroll
    for (int rr = 0; rr < 4; ++rr)
      Cs[(mw + q * 4 + rr) * 264 + nw + nt * 16 + r] = f2bf(acc[nt][rr]);
  __syncthreads();

  // write xpb coalesced: 64 B contiguous per thread
  {
    int pix = t >> 3, c32 = (t & 7) * 32;
    unsigned short* o = xpb + ((size_t)b * HWP + pix0 + pix) * CC + c32;
#pragma unroll
    for (int j = 0; j < 4; ++j)
      *(uint4*)(o + j * 8) = *(const uint4*)&Cs[pix * 264 + c32 + j * 8];
  }

  // offset epilogue: offs[pix, o] = sum_c Cs[pix][c] * wb[o][c] + off_b[o]
  {
    int mw2 = (w & 1) * 16;    // pixel tile
    int nw2 = (w >> 1) * 16;   // o tile (0 or 16)
    f32x4 oacc = {};
#pragma unroll
    for (int ks = 0; ks < CC; ks += 32) {
      bf16x8 a = *(const bf16x8*)&Cs[(mw2 + r) * 264 + ks + q * 8];
      uint4 u = *(const uint4*)(wb + (nw2 + r) * 256 + ks + q * 8);
      bf16x8 bb;
      ((uint4*)&bb)[0] = u;
      oacc = __builtin_amdgcn_mfma_f32_16x16x32_bf16(a, bb, oacc, 0, 0, 0);
    }
    int o = nw2 + r;
    if (o < 18) {
      float ob = off_b[o];
      size_t base = ((size_t)b * HWP + pix0 + mw2 + q * 4) * 20 + o;
#pragma unroll
      for (int rr = 0; rr < 4; ++rr)
        offs[base + (size_t)rr * 20] = oacc[rr] + ob;
    }
  }
}

// ---- gather + depthwise: 16 pixels/block, XCD-swizzled; LDS-staged NCHW writes.
// R5-proven config — 96 VGPR, ~50% occupancy. Hard-won pitfalls:
//  * NO launch-bounds min-wave arg (R6: VGPR cap 64 -> scratch spills, 3x slower)
//  * NO nontemporal output stores (R4: 4x WRITE_SIZE amplification)
//  * NO 8-ch/lane half-wave scheme (R8: VGPR 176, occupancy 9%, +25% time)
__global__ __launch_bounds__(256) void k_gather(const unsigned short* __restrict__ xp,
                                                const float* __restrict__ offs,
                                                const float* __restrict__ dw,
                                                float* __restrict__ out) {
  __shared__ float Cs[16][257];
  int bid = blockIdx.x;
  int sb  = (bid & 7) * 144 + (bid >> 3);
  int pix0 = sb * 16;
  int wave = threadIdx.x >> 6;
  int lane = threadIdx.x & 63;
  int c0 = lane * 4;

  float dwr[4][9];
#pragma unroll
  for (int i = 0; i < 4; ++i)
#pragma unroll
    for (int kk = 0; kk < 9; ++kk)
      dwr[i][kk] = dw[(c0 + i) * 9 + kk];

  int b   = pix0 / HWP;
  int hw0 = pix0 - b * HWP;
  const unsigned short* xb = xp + (size_t)b * HWP * CC;

#pragma unroll
  for (int p4 = 0; p4 < 4; ++p4) {
    int ip  = wave * 4 + p4;
    int hw  = hw0 + ip;
    int h   = hw / WW;
    int w   = hw - h * WW;

    const float* op = offs + (size_t)(pix0 + ip) * 20;
    float4 q0 = *(const float4*)(op + 0);
    float4 q1 = *(const float4*)(op + 4);
    float4 q2 = *(const float4*)(op + 8);
    float4 q3 = *(const float4*)(op + 12);
    float2 q4 = *(const float2*)(op + 16);
    float offr[18] = {q0.x,q0.y,q0.z,q0.w, q1.x,q1.y,q1.z,q1.w,
                      q2.x,q2.y,q2.z,q2.w, q3.x,q3.y,q3.z,q3.w, q4.x,q4.y};

    float acc0 = 0.f, acc1 = 0.f, acc2 = 0.f, acc3 = 0.f;
#pragma unroll
    for (int kk = 0; kk < 9; ++kk) {
      float y = (float)(h - 1 + kk / 3) + offr[2 * kk];
      float x = (float)(w - 1 + kk % 3) + offr[2 * kk + 1];
      float y0f = floorf(y), x0f = floorf(x);
      float fy = y - y0f, fx = x - x0f;
      int y0 = (int)y0f, x0 = (int)x0f;
      int y1 = y0 + 1, x1 = x0 + 1;
      bool vy0 = (y0 >= 0) & (y0 < HH);
      bool vy1 = (y1 >= 0) & (y1 < HH);
      bool vx0 = (x0 >= 0) & (x0 < WW);
      bool vx1 = (x1 >= 0) & (x1 < WW);
      int y0c = y0 < 0 ? 0 : (y0 > HH - 1 ? HH - 1 : y0);
      int y1c = y1 < 0 ? 0 : (y1 > HH - 1 ? HH - 1 : y1);
      int x0c = x0 < 0 ? 0 : (x0 > WW - 1 ? WW - 1 : x0);
      int x1c = x1 < 0 ? 0 : (x1 > WW - 1 ? WW - 1 : x1);
      float w00 = (1.f - fy) * (1.f - fx) * ((vy0 && vx0) ? 1.f : 0.f);
      float w01 = (1.f - fy) * fx         * ((vy0 && vx1) ? 1.f : 0.f);
      float w10 = fy * (1.f - fx)         * ((vy1 && vx0) ? 1.f : 0.f);
      float w11 = fy * fx                 * ((vy1 && vx1) ? 1.f : 0.f);

      uint2 u00 = *(const uint2*)(xb + (size_t)(y0c * WW + x0c) * CC + c0);
      uint2 u01 = *(const uint2*)(xb + (size_t)(y0c * WW + x1c) * CC + c0);
      uint2 u10 = *(const uint2*)(xb + (size_t)(y1c * WW + x0c) * CC + c0);
      uint2 u11 = *(const uint2*)(xb + (size_t)(y1c * WW + x1c) * CC + c0);

      float s0 = w00 * bf_lo(u00.x) + w01 * bf_lo(u01.x) + w10 * bf_lo(u10.x) + w11 * bf_lo(u11.x);
      float s1 = w00 * bf_hi(u00.x) + w01 * bf_hi(u01.x) + w10 * bf_hi(u10.x) + w11 * bf_hi(u11.x);
      float s2 = w00 * bf_lo(u00.y) + w01 * bf_lo(u01.y) + w10 * bf_lo(u10.y) + w11 * bf_lo(u11.y);
      float s3 = w00 * bf_hi(u00.y) + w01 * bf_hi(u01.y) + w10 * bf_hi(u10.y) + w11 * bf_hi(u11.y);

      acc0 += dwr[0][kk] * s0;
      acc1 += dwr[1][kk] * s1;
      acc2 += dwr[2][kk] * s2;
      acc3 += dwr[3][kk] * s3;
    }
    *(float4*)&Cs[ip][c0] = make_float4(acc0, acc1, acc2, acc3);
  }
  __syncthreads();
  // write-out: thread t = channel, 16 consecutive pixels = 64 B contiguous per thread.
  int ch = threadIdx.x;
  float* ob = out + (size_t)b * CC * HWP + (size_t)ch * HWP + hw0;
#pragma unroll
  for (int p4 = 0; p4 < 4; ++p4) {
    float4 v = make_float4(Cs[p4 * 4 + 0][ch], Cs[p4 * 4 + 1][ch],
                           Cs[p4 * 4 + 2][ch], Cs[p4 * 4 + 3][ch]);
    *(float4*)(ob + p4 * 4) = v;
  }
}

extern "C" void kernel_launch(void* const* d_in, const int* in_sizes, int n_in,
                              void* d_out, int out_size, void* d_ws, size_t ws_size,
                              hipStream_t stream) {
  (void)in_sizes; (void)n_in; (void)out_size; (void)ws_size;
  const float* x     = (const float*)d_in[0];
  const float* pw_w  = (const float*)d_in[1];
  const float* off_w = (const float*)d_in[2];
  const float* off_b = (const float*)d_in[3];
  const float* dw_w  = (const float*)d_in[4];
  float* out = (float*)d_out;

  char* ws = (char*)d_ws;
  unsigned short* xpb = (unsigned short*)ws;                 // B*HW*C bf16 = 9,437,184 B
  float* offs = (float*)(ws + 9437184);                      // B*HW*20 f32 = 1,474,560 B
  unsigned short* wb  = (unsigned short*)(ws + 10911744);    // 32*256 bf16 = 16,384 B
  unsigned short* pwb = (unsigned short*)(ws + 10928128);    // 256*256 bf16 = 131,072 B

  k_prep <<<(CC * CC + 32 * CC) / 1024, 256, 0, stream>>>(pw_w, off_w, pwb, wb);
  k_main <<<dim3(HWP / 32, 1, NB), 256, 0, stream>>>(x, pwb, wb, off_b, xpb, offs);
  k_gather<<<NB * HWP / 16, 256, 0, stream>>>(xpb, offs, dw_w, out);
}

// Round 10
// 131.554 us; speedup vs baseline: 1.7889x; 1.0241x over previous
//
#include <hip/hip_runtime.h>
#include <hip/hip_bf16.h>

#define HWP 9216   // H*W
#define HH  96
#define WW  96
#define CC  256    // Cin == Cout
#define NB  2

typedef __attribute__((ext_vector_type(8))) short bf16x8;
typedef __attribute__((ext_vector_type(4))) float f32x4;

__device__ inline unsigned short f2bf(float f) {
  union { __hip_bfloat16 h; unsigned short u; } cvt;
  cvt.h = __float2bfloat16(f);
  return cvt.u;
}
__device__ inline float bf_lo(unsigned int u) { return __uint_as_float(u << 16); }
__device__ inline float bf_hi(unsigned int u) { return __uint_as_float(u & 0xffff0000u); }

// ---- prep: pw_w (256x256) f32->bf16 ; off_w (18x256) f32->bf16 zero-padded to
// (32x256) ; dw_w (256x9) f32 -> transposed dwt (9x256) f32
__global__ __launch_bounds__(256) void k_prep(const float* __restrict__ pw,
                                              const float* __restrict__ ow,
                                              const float* __restrict__ dw,
                                              unsigned short* __restrict__ pwb,
                                              unsigned short* __restrict__ wb,
                                              float* __restrict__ dwt) {
  int i = (blockIdx.x * 256 + threadIdx.x) * 4;
  if (i < CC * CC) {
    float4 v = *(const float4*)(pw + i);
    ushort4 o = make_ushort4(f2bf(v.x), f2bf(v.y), f2bf(v.z), f2bf(v.w));
    *(ushort4*)(pwb + i) = o;
  } else if (i < CC * CC + 32 * 256) {
    int j = i - CC * CC;           // 0..8191
    int row = j >> 8;
    ushort4 o = make_ushort4(0, 0, 0, 0);
    if (row < 18) {
      float4 v = *(const float4*)(ow + j);
      o = make_ushort4(f2bf(v.x), f2bf(v.y), f2bf(v.z), f2bf(v.w));
    }
    *(ushort4*)(wb + j) = o;
  } else {
    int j2 = i - (CC * CC + 32 * 256);   // 0..2303 (step 4)
    if (j2 < 9 * 256) {
      int kk = j2 >> 8;
      int ch = j2 & 255;
      float4 v = make_float4(dw[(ch + 0) * 9 + kk], dw[(ch + 1) * 9 + kk],
                             dw[(ch + 2) * 9 + kk], dw[(ch + 3) * 9 + kk]);
      *(float4*)(dwt + j2) = v;
    }
  }
}

// ---- fused: xp = pw_w . x  (bf16 MFMA, 32 pix x 256 ch per block, BK=32)
//            + offs = off_w . xp + off_b  (MFMA epilogue on the Cs tile)
// R5-proven form. Pitfalls: register-prefetch pipelining (R6/R7) REGRESSED;
// BK=64 (R9) REGRESSED ~3us — LDS 58KB halves blocks/CU. Keep BK=32.
__global__ __launch_bounds__(256) void k_main(const float* __restrict__ x,
                                              const unsigned short* __restrict__ pwb,
                                              const unsigned short* __restrict__ wb,
                                              const float* __restrict__ off_b,
                                              unsigned short* __restrict__ xpb,
                                              float* __restrict__ offs) {
  __shared__ unsigned short As[32 * 40];    // [pix][k]
  __shared__ unsigned short Bs[256 * 40];   // [n][k]
  __shared__ unsigned short Cs[32 * 264];   // [pix][ch] bf16, pad 264

  int b    = blockIdx.z;
  int pix0 = blockIdx.x * 32;
  int t    = threadIdx.x;
  int lane = t & 63;
  int w    = t >> 6;
  int mw = (w & 1) * 16;     // wave pixel tile
  int nw = (w >> 1) * 128;   // wave channel half
  int r = lane & 15, q = lane >> 4;

  f32x4 acc[8] = {};

  const float* xg = x + (size_t)b * CC * HWP + pix0;
  int sc = t >> 3;           // channel within 32-chunk
  int sp = (t & 7) * 4;      // pixel offset

  for (int k0 = 0; k0 < CC; k0 += 32) {
    // A: coalesced float4 (4 pixels, 1 channel) -> in-register cvt -> transposed LDS
    f32x4 xv = __builtin_nontemporal_load((const f32x4*)(xg + (size_t)(k0 + sc) * HWP + sp));
    As[(sp + 0) * 40 + sc] = f2bf(xv.x);
    As[(sp + 1) * 40 + sc] = f2bf(xv.y);
    As[(sp + 2) * 40 + sc] = f2bf(xv.z);
    As[(sp + 3) * 40 + sc] = f2bf(xv.w);
    // B: 256 rows x 32 k slice of pwb
    const unsigned short* bg = pwb + k0;
#pragma unroll
    for (int rep = 0; rep < 4; ++rep) {
      int n  = rep * 64 + (t >> 2);
      int c8 = (t & 3) * 8;
      *(uint4*)&Bs[n * 40 + c8] = *(const uint4*)(bg + n * 256 + c8);
    }
    __syncthreads();
    bf16x8 a = *(const bf16x8*)&As[(mw + r) * 40 + q * 8];
#pragma unroll
    for (int nt = 0; nt < 8; ++nt) {
      bf16x8 bb = *(const bf16x8*)&Bs[(nw + nt * 16 + r) * 40 + q * 8];
      acc[nt] = __builtin_amdgcn_mfma_f32_16x16x32_bf16(a, bb, acc[nt], 0, 0, 0);
    }
    __syncthreads();
  }

  // C/D: col = lane&15 (ch), row = q*4+rr (pix) -> Cs[pix][ch] bf16
#pragma unroll
  for (int nt = 0; nt < 8; ++nt)
#pragma unroll
    for (int rr = 0; rr < 4; ++rr)
      Cs[(mw + q * 4 + rr) * 264 + nw + nt * 16 + r] = f2bf(acc[nt][rr]);
  __syncthreads();

  // write xpb coalesced: 64 B contiguous per thread
  {
    int pix = t >> 3, c32 = (t & 7) * 32;
    unsigned short* o = xpb + ((size_t)b * HWP + pix0 + pix) * CC + c32;
#pragma unroll
    for (int j = 0; j < 4; ++j)
      *(uint4*)(o + j * 8) = *(const uint4*)&Cs[pix * 264 + c32 + j * 8];
  }

  // offset epilogue: offs[pix, o] = sum_c Cs[pix][c] * wb[o][c] + off_b[o]
  {
    int mw2 = (w & 1) * 16;    // pixel tile
    int nw2 = (w >> 1) * 16;   // o tile (0 or 16)
    f32x4 oacc = {};
#pragma unroll
    for (int ks = 0; ks < CC; ks += 32) {
      bf16x8 a = *(const bf16x8*)&Cs[(mw2 + r) * 264 + ks + q * 8];
      uint4 u = *(const uint4*)(wb + (nw2 + r) * 256 + ks + q * 8);
      bf16x8 bb;
      ((uint4*)&bb)[0] = u;
      oacc = __builtin_amdgcn_mfma_f32_16x16x32_bf16(a, bb, oacc, 0, 0, 0);
    }
    int o = nw2 + r;
    if (o < 18) {
      float ob = off_b[o];
      size_t base = ((size_t)b * HWP + pix0 + mw2 + q * 4) * 20 + o;
#pragma unroll
      for (int rr = 0; rr < 4; ++rr)
        offs[base + (size_t)rr * 20] = oacc[rr] + ob;
    }
  }
}

// ---- gather + depthwise: 16 pixels/block, XCD-swizzled; LDS-staged NCHW writes.
// Tap-outer / pixel-inner loop: per tap, one float4 dwt load + one float2 offs
// load per pixel — drops dwr[4][9] (36 VGPR) + offr[18] from the live set.
// Hard-won pitfalls:
//  * NO launch-bounds min-wave arg (R6: forced VGPR 64 -> scratch spills, 3x)
//  * NO nontemporal output stores (R4: 4x WRITE_SIZE amplification)
//  * NO 8-ch/lane half-wave scheme (R8: VGPR 176, occupancy 9%, +25% time)
__global__ __launch_bounds__(256) void k_gather(const unsigned short* __restrict__ xp,
                                                const float* __restrict__ offs,
                                                const float* __restrict__ dwt,
                                                float* __restrict__ out) {
  __shared__ float Cs[16][257];
  int bid = blockIdx.x;
  int sb  = (bid & 7) * 144 + (bid >> 3);
  int pix0 = sb * 16;
  int wave = threadIdx.x >> 6;
  int lane = threadIdx.x & 63;
  int c0 = lane * 4;

  int b   = pix0 / HWP;
  int hw0 = pix0 - b * HWP;
  const unsigned short* xb = xp + (size_t)b * HWP * CC;
  const float* opb = offs + (size_t)pix0 * 20;

  int h4[4], w4[4];
#pragma unroll
  for (int p4 = 0; p4 < 4; ++p4) {
    int hw = hw0 + wave * 4 + p4;
    h4[p4] = hw / WW;
    w4[p4] = hw - h4[p4] * WW;
  }

  float acc[4][4] = {};
#pragma unroll
  for (int kk = 0; kk < 9; ++kk) {
    float4 dv = *(const float4*)(dwt + kk * 256 + c0);
    int dy = kk / 3 - 1, dx = kk % 3 - 1;
#pragma unroll
    for (int p4 = 0; p4 < 4; ++p4) {
      int ip = wave * 4 + p4;
      float2 o2 = *(const float2*)(opb + ip * 20 + 2 * kk);
      float y = (float)(h4[p4] + dy) + o2.x;
      float x = (float)(w4[p4] + dx) + o2.y;
      float y0f = floorf(y), x0f = floorf(x);
      float fy = y - y0f, fx = x - x0f;
      int y0 = (int)y0f, x0 = (int)x0f;
      int y1 = y0 + 1, x1 = x0 + 1;
      bool vy0 = (y0 >= 0) & (y0 < HH);
      bool vy1 = (y1 >= 0) & (y1 < HH);
      bool vx0 = (x0 >= 0) & (x0 < WW);
      bool vx1 = (x1 >= 0) & (x1 < WW);
      int y0c = y0 < 0 ? 0 : (y0 > HH - 1 ? HH - 1 : y0);
      int y1c = y1 < 0 ? 0 : (y1 > HH - 1 ? HH - 1 : y1);
      int x0c = x0 < 0 ? 0 : (x0 > WW - 1 ? WW - 1 : x0);
      int x1c = x1 < 0 ? 0 : (x1 > WW - 1 ? WW - 1 : x1);
      float w00 = (1.f - fy) * (1.f - fx) * ((vy0 && vx0) ? 1.f : 0.f);
      float w01 = (1.f - fy) * fx         * ((vy0 && vx1) ? 1.f : 0.f);
      float w10 = fy * (1.f - fx)         * ((vy1 && vx0) ? 1.f : 0.f);
      float w11 = fy * fx                 * ((vy1 && vx1) ? 1.f : 0.f);

      uint2 u00 = *(const uint2*)(xb + (size_t)(y0c * WW + x0c) * CC + c0);
      uint2 u01 = *(const uint2*)(xb + (size_t)(y0c * WW + x1c) * CC + c0);
      uint2 u10 = *(const uint2*)(xb + (size_t)(y1c * WW + x0c) * CC + c0);
      uint2 u11 = *(const uint2*)(xb + (size_t)(y1c * WW + x1c) * CC + c0);

      float s0 = w00 * bf_lo(u00.x) + w01 * bf_lo(u01.x) + w10 * bf_lo(u10.x) + w11 * bf_lo(u11.x);
      float s1 = w00 * bf_hi(u00.x) + w01 * bf_hi(u01.x) + w10 * bf_hi(u10.x) + w11 * bf_hi(u11.x);
      float s2 = w00 * bf_lo(u00.y) + w01 * bf_lo(u01.y) + w10 * bf_lo(u10.y) + w11 * bf_lo(u11.y);
      float s3 = w00 * bf_hi(u00.y) + w01 * bf_hi(u01.y) + w10 * bf_hi(u10.y) + w11 * bf_hi(u11.y);

      acc[p4][0] += dv.x * s0;
      acc[p4][1] += dv.y * s1;
      acc[p4][2] += dv.z * s2;
      acc[p4][3] += dv.w * s3;
    }
  }
#pragma unroll
  for (int p4 = 0; p4 < 4; ++p4)
    *(float4*)&Cs[wave * 4 + p4][c0] =
        make_float4(acc[p4][0], acc[p4][1], acc[p4][2], acc[p4][3]);
  __syncthreads();
  // write-out: thread t = channel, 16 consecutive pixels = 64 B contiguous per thread.
  int ch = threadIdx.x;
  float* ob = out + (size_t)b * CC * HWP + (size_t)ch * HWP + hw0;
#pragma unroll
  for (int p4 = 0; p4 < 4; ++p4) {
    float4 v = make_float4(Cs[p4 * 4 + 0][ch], Cs[p4 * 4 + 1][ch],
                           Cs[p4 * 4 + 2][ch], Cs[p4 * 4 + 3][ch]);
    *(float4*)(ob + p4 * 4) = v;
  }
}

extern "C" void kernel_launch(void* const* d_in, const int* in_sizes, int n_in,
                              void* d_out, int out_size, void* d_ws, size_t ws_size,
                              hipStream_t stream) {
  (void)in_sizes; (void)n_in; (void)out_size; (void)ws_size;
  const float* x     = (const float*)d_in[0];
  const float* pw_w  = (const float*)d_in[1];
  const float* off_w = (const float*)d_in[2];
  const float* off_b = (const float*)d_in[3];
  const float* dw_w  = (const float*)d_in[4];
  float* out = (float*)d_out;

  char* ws = (char*)d_ws;
  unsigned short* xpb = (unsigned short*)ws;                 // B*HW*C bf16 = 9,437,184 B
  float* offs = (float*)(ws + 9437184);                      // B*HW*20 f32 = 1,474,560 B
  unsigned short* wb  = (unsigned short*)(ws + 10911744);    // 32*256 bf16 = 16,384 B
  unsigned short* pwb = (unsigned short*)(ws + 10928128);    // 256*256 bf16 = 131,072 B
  float* dwt          = (float*)(ws + 11059200);             // 9*256 f32 = 9,216 B

  k_prep <<<75, 256, 0, stream>>>(pw_w, off_w, dw_w, pwb, wb, dwt);
  k_main <<<dim3(HWP / 32, 1, NB), 256, 0, stream>>>(x, pwb, wb, off_b, xpb, offs);
  k_gather<<<NB * HWP / 16, 256, 0, stream>>>(xpb, offs, dwt, out);
}

// Round 11
// 130.667 us; speedup vs baseline: 1.8011x; 1.0068x over previous
//
#include <hip/hip_runtime.h>
#include <hip/hip_bf16.h>

#define HWP 9216   // H*W
#define HH  96
#define WW  96
#define CC  256    // Cin == Cout
#define NB  2

typedef __attribute__((ext_vector_type(8))) short bf16x8;
typedef __attribute__((ext_vector_type(4))) float f32x4;

__device__ inline unsigned short f2bf(float f) {
  union { __hip_bfloat16 h; unsigned short u; } cvt;
  cvt.h = __float2bfloat16(f);
  return cvt.u;
}
__device__ inline float bf_lo(unsigned int u) { return __uint_as_float(u << 16); }
__device__ inline float bf_hi(unsigned int u) { return __uint_as_float(u & 0xffff0000u); }

// ---- prep: pw_w (256x256) f32->bf16 ; off_w (18x256) f32->bf16 zero-padded to
// (32x256) ; dw_w (256x9) f32 -> transposed dwt (9x256) f32
__global__ __launch_bounds__(256) void k_prep(const float* __restrict__ pw,
                                              const float* __restrict__ ow,
                                              const float* __restrict__ dw,
                                              unsigned short* __restrict__ pwb,
                                              unsigned short* __restrict__ wb,
                                              float* __restrict__ dwt) {
  int i = (blockIdx.x * 256 + threadIdx.x) * 4;
  if (i < CC * CC) {
    float4 v = *(const float4*)(pw + i);
    ushort4 o = make_ushort4(f2bf(v.x), f2bf(v.y), f2bf(v.z), f2bf(v.w));
    *(ushort4*)(pwb + i) = o;
  } else if (i < CC * CC + 32 * 256) {
    int j = i - CC * CC;           // 0..8191
    int row = j >> 8;
    ushort4 o = make_ushort4(0, 0, 0, 0);
    if (row < 18) {
      float4 v = *(const float4*)(ow + j);
      o = make_ushort4(f2bf(v.x), f2bf(v.y), f2bf(v.z), f2bf(v.w));
    }
    *(ushort4*)(wb + j) = o;
  } else {
    int j2 = i - (CC * CC + 32 * 256);   // 0..2303 (step 4)
    if (j2 < 9 * 256) {
      int kk = j2 >> 8;
      int ch = j2 & 255;
      float4 v = make_float4(dw[(ch + 0) * 9 + kk], dw[(ch + 1) * 9 + kk],
                             dw[(ch + 2) * 9 + kk], dw[(ch + 3) * 9 + kk]);
      *(float4*)(dwt + j2) = v;
    }
  }
}

// ---- fused: xp = pw_w . x  (bf16 MFMA, 32 pix x 256 ch per block, BK=32)
//            + offs = off_w . xp + off_b  (MFMA epilogue on the Cs tile)
// 1-D grid, XCD-aligned: block g -> XCD class e=g%8 produces pixel strip
// [e*1152, (e+1)*1152) per batch, so k_gather (same decode) finds xp in the
// LOCAL per-XCD L2. Pitfalls: register-prefetch pipelining (R6/R7) REGRESSED;
// BK=64 (R9) REGRESSED — LDS 58KB halves blocks/CU. Keep BK=32.
__global__ __launch_bounds__(256) void k_main(const float* __restrict__ x,
                                              const unsigned short* __restrict__ pwb,
                                              const unsigned short* __restrict__ wb,
                                              const float* __restrict__ off_b,
                                              unsigned short* __restrict__ xpb,
                                              float* __restrict__ offs) {
  __shared__ unsigned short As[32 * 40];    // [pix][k]
  __shared__ unsigned short Bs[256 * 40];   // [n][k]
  __shared__ unsigned short Cs[32 * 264];   // [pix][ch] bf16, pad 264

  // XCD-aligned decode: g -> (e, b, m); strip block x = e*36 + m
  int g   = blockIdx.x;          // 0..575
  int e   = g & 7;
  int idx = g >> 3;              // 0..71
  int b   = idx / 36;
  int m   = idx - b * 36;        // 0..35
  int pix0 = (e * 36 + m) * 32;  // local pixel within batch

  int t    = threadIdx.x;
  int lane = t & 63;
  int w    = t >> 6;
  int mw = (w & 1) * 16;     // wave pixel tile
  int nw = (w >> 1) * 128;   // wave channel half
  int r = lane & 15, q = lane >> 4;

  f32x4 acc[8] = {};

  const float* xg = x + (size_t)b * CC * HWP + pix0;
  int sc = t >> 3;           // channel within 32-chunk
  int sp = (t & 7) * 4;      // pixel offset

  for (int k0 = 0; k0 < CC; k0 += 32) {
    // A: coalesced float4 (4 pixels, 1 channel) -> in-register cvt -> transposed LDS
    f32x4 xv = __builtin_nontemporal_load((const f32x4*)(xg + (size_t)(k0 + sc) * HWP + sp));
    As[(sp + 0) * 40 + sc] = f2bf(xv.x);
    As[(sp + 1) * 40 + sc] = f2bf(xv.y);
    As[(sp + 2) * 40 + sc] = f2bf(xv.z);
    As[(sp + 3) * 40 + sc] = f2bf(xv.w);
    // B: 256 rows x 32 k slice of pwb
    const unsigned short* bg = pwb + k0;
#pragma unroll
    for (int rep = 0; rep < 4; ++rep) {
      int n  = rep * 64 + (t >> 2);
      int c8 = (t & 3) * 8;
      *(uint4*)&Bs[n * 40 + c8] = *(const uint4*)(bg + n * 256 + c8);
    }
    __syncthreads();
    bf16x8 a = *(const bf16x8*)&As[(mw + r) * 40 + q * 8];
#pragma unroll
    for (int nt = 0; nt < 8; ++nt) {
      bf16x8 bb = *(const bf16x8*)&Bs[(nw + nt * 16 + r) * 40 + q * 8];
      acc[nt] = __builtin_amdgcn_mfma_f32_16x16x32_bf16(a, bb, acc[nt], 0, 0, 0);
    }
    __syncthreads();
  }

  // C/D: col = lane&15 (ch), row = q*4+rr (pix) -> Cs[pix][ch] bf16
#pragma unroll
  for (int nt = 0; nt < 8; ++nt)
#pragma unroll
    for (int rr = 0; rr < 4; ++rr)
      Cs[(mw + q * 4 + rr) * 264 + nw + nt * 16 + r] = f2bf(acc[nt][rr]);
  __syncthreads();

  // write xpb coalesced: 64 B contiguous per thread
  {
    int pix = t >> 3, c32 = (t & 7) * 32;
    unsigned short* o = xpb + ((size_t)b * HWP + pix0 + pix) * CC + c32;
#pragma unroll
    for (int j = 0; j < 4; ++j)
      *(uint4*)(o + j * 8) = *(const uint4*)&Cs[pix * 264 + c32 + j * 8];
  }

  // offset epilogue: offs[pix, o] = sum_c Cs[pix][c] * wb[o][c] + off_b[o]
  {
    int mw2 = (w & 1) * 16;    // pixel tile
    int nw2 = (w >> 1) * 16;   // o tile (0 or 16)
    f32x4 oacc = {};
#pragma unroll
    for (int ks = 0; ks < CC; ks += 32) {
      bf16x8 a = *(const bf16x8*)&Cs[(mw2 + r) * 264 + ks + q * 8];
      uint4 u = *(const uint4*)(wb + (nw2 + r) * 256 + ks + q * 8);
      bf16x8 bb;
      ((uint4*)&bb)[0] = u;
      oacc = __builtin_amdgcn_mfma_f32_16x16x32_bf16(a, bb, oacc, 0, 0, 0);
    }
    int o = nw2 + r;
    if (o < 18) {
      float ob = off_b[o];
      size_t base = ((size_t)b * HWP + pix0 + mw2 + q * 4) * 20 + o;
#pragma unroll
      for (int rr = 0; rr < 4; ++rr)
        offs[base + (size_t)rr * 20] = oacc[rr] + ob;
    }
  }
}

// ---- gather + depthwise: 16 pixels/block, XCD-ALIGNED to k_main's strips.
// Block g -> XCD class e=g%8 gathers exactly the rows produced by k_main's
// class-e blocks -> bulk corner loads hit LOCAL L2 (only ~2-row halo remote).
// Tap-outer / pixel-inner loop. Hard-won pitfalls:
//  * NO launch-bounds min-wave arg (R6: forced VGPR 64 -> scratch spills, 3x)
//  * NO nontemporal output stores (R4: 4x WRITE_SIZE amplification)
//  * NO 8-ch/lane half-wave scheme (R8: VGPR 176, occupancy 9%, +25% time)
__global__ __launch_bounds__(256) void k_gather(const unsigned short* __restrict__ xp,
                                                const float* __restrict__ offs,
                                                const float* __restrict__ dwt,
                                                float* __restrict__ out) {
  __shared__ float Cs[16][257];
  // XCD-aligned decode: g -> (e, b, m2); chunk c = e*72 + m2 (16 px each)
  int g   = blockIdx.x;          // 0..1151
  int e   = g & 7;
  int idx = g >> 3;              // 0..143
  int b   = idx / 72;
  int m2  = idx - b * 72;        // 0..71
  int c   = e * 72 + m2;         // 0..575
  int pix0 = b * HWP + c * 16;   // global pixel

  int wave = threadIdx.x >> 6;
  int lane = threadIdx.x & 63;
  int c0 = lane * 4;

  int hw0 = pix0 - b * HWP;
  const unsigned short* xb = xp + (size_t)b * HWP * CC;
  const float* opb = offs + (size_t)pix0 * 20;

  int h4[4], w4[4];
#pragma unroll
  for (int p4 = 0; p4 < 4; ++p4) {
    int hw = hw0 + wave * 4 + p4;
    h4[p4] = hw / WW;
    w4[p4] = hw - h4[p4] * WW;
  }

  float acc[4][4] = {};
#pragma unroll
  for (int kk = 0; kk < 9; ++kk) {
    float4 dv = *(const float4*)(dwt + kk * 256 + c0);
    int dy = kk / 3 - 1, dx = kk % 3 - 1;
#pragma unroll
    for (int p4 = 0; p4 < 4; ++p4) {
      int ip = wave * 4 + p4;
      float2 o2 = *(const float2*)(opb + ip * 20 + 2 * kk);
      float y = (float)(h4[p4] + dy) + o2.x;
      float x = (float)(w4[p4] + dx) + o2.y;
      float y0f = floorf(y), x0f = floorf(x);
      float fy = y - y0f, fx = x - x0f;
      int y0 = (int)y0f, x0 = (int)x0f;
      int y1 = y0 + 1, x1 = x0 + 1;
      bool vy0 = (y0 >= 0) & (y0 < HH);
      bool vy1 = (y1 >= 0) & (y1 < HH);
      bool vx0 = (x0 >= 0) & (x0 < WW);
      bool vx1 = (x1 >= 0) & (x1 < WW);
      int y0c = y0 < 0 ? 0 : (y0 > HH - 1 ? HH - 1 : y0);
      int y1c = y1 < 0 ? 0 : (y1 > HH - 1 ? HH - 1 : y1);
      int x0c = x0 < 0 ? 0 : (x0 > WW - 1 ? WW - 1 : x0);
      int x1c = x1 < 0 ? 0 : (x1 > WW - 1 ? WW - 1 : x1);
      float w00 = (1.f - fy) * (1.f - fx) * ((vy0 && vx0) ? 1.f : 0.f);
      float w01 = (1.f - fy) * fx         * ((vy0 && vx1) ? 1.f : 0.f);
      float w10 = fy * (1.f - fx)         * ((vy1 && vx0) ? 1.f : 0.f);
      float w11 = fy * fx                 * ((vy1 && vx1) ? 1.f : 0.f);

      uint2 u00 = *(const uint2*)(xb + (size_t)(y0c * WW + x0c) * CC + c0);
      uint2 u01 = *(const uint2*)(xb + (size_t)(y0c * WW + x1c) * CC + c0);
      uint2 u10 = *(const uint2*)(xb + (size_t)(y1c * WW + x0c) * CC + c0);
      uint2 u11 = *(const uint2*)(xb + (size_t)(y1c * WW + x1c) * CC + c0);

      float s0 = w00 * bf_lo(u00.x) + w01 * bf_lo(u01.x) + w10 * bf_lo(u10.x) + w11 * bf_lo(u11.x);
      float s1 = w00 * bf_hi(u00.x) + w01 * bf_hi(u01.x) + w10 * bf_hi(u10.x) + w11 * bf_hi(u11.x);
      float s2 = w00 * bf_lo(u00.y) + w01 * bf_lo(u01.y) + w10 * bf_lo(u10.y) + w11 * bf_lo(u11.y);
      float s3 = w00 * bf_hi(u00.y) + w01 * bf_hi(u01.y) + w10 * bf_hi(u10.y) + w11 * bf_hi(u11.y);

      acc[p4][0] += dv.x * s0;
      acc[p4][1] += dv.y * s1;
      acc[p4][2] += dv.z * s2;
      acc[p4][3] += dv.w * s3;
    }
  }
#pragma unroll
  for (int p4 = 0; p4 < 4; ++p4)
    *(float4*)&Cs[wave * 4 + p4][c0] =
        make_float4(acc[p4][0], acc[p4][1], acc[p4][2], acc[p4][3]);
  __syncthreads();
  // write-out: thread t = channel, 16 consecutive pixels = 64 B contiguous per thread.
  int ch = threadIdx.x;
  float* ob = out + (size_t)b * CC * HWP + (size_t)ch * HWP + hw0;
#pragma unroll
  for (int p4 = 0; p4 < 4; ++p4) {
    float4 v = make_float4(Cs[p4 * 4 + 0][ch], Cs[p4 * 4 + 1][ch],
                           Cs[p4 * 4 + 2][ch], Cs[p4 * 4 + 3][ch]);
    *(float4*)(ob + p4 * 4) = v;
  }
}

extern "C" void kernel_launch(void* const* d_in, const int* in_sizes, int n_in,
                              void* d_out, int out_size, void* d_ws, size_t ws_size,
                              hipStream_t stream) {
  (void)in_sizes; (void)n_in; (void)out_size; (void)ws_size;
  const float* x     = (const float*)d_in[0];
  const float* pw_w  = (const float*)d_in[1];
  const float* off_w = (const float*)d_in[2];
  const float* off_b = (const float*)d_in[3];
  const float* dw_w  = (const float*)d_in[4];
  float* out = (float*)d_out;

  char* ws = (char*)d_ws;
  unsigned short* xpb = (unsigned short*)ws;                 // B*HW*C bf16 = 9,437,184 B
  float* offs = (float*)(ws + 9437184);                      // B*HW*20 f32 = 1,474,560 B
  unsigned short* wb  = (unsigned short*)(ws + 10911744);    // 32*256 bf16 = 16,384 B
  unsigned short* pwb = (unsigned short*)(ws + 10928128);    // 256*256 bf16 = 131,072 B
  float* dwt          = (float*)(ws + 11059200);             // 9*256 f32 = 9,216 B

  k_prep <<<75, 256, 0, stream>>>(pw_w, off_w, dw_w, pwb, wb, dwt);
  k_main <<<576, 256, 0, stream>>>(x, pwb, wb, off_b, xpb, offs);
  k_gather<<<1152, 256, 0, stream>>>(xpb, offs, dwt, out);
}